// Round 6
// baseline (1190.555 us; speedup 1.0000x reference)
//
#include <hip/hip_runtime.h>
#include <hip/hip_bf16.h>

#define B_ 32
#define T_ 512
#define L_ 16
#define F_ 128
#define H_ 128
#define C_ 61
#define NF_ (B_*T_)   // 16384 frames
#define CH_ 4096      // frames per rnn1 chunk

typedef unsigned int u32;
typedef unsigned short u16;
typedef __attribute__((ext_vector_type(8))) short s16x8;
typedef __attribute__((ext_vector_type(4))) float f32x4;

__device__ __forceinline__ float bflo(u32 v){ return __uint_as_float(v << 16); }
__device__ __forceinline__ float bfhi(u32 v){ return __uint_as_float(v & 0xffff0000u); }
__device__ __forceinline__ u16 f2bf(float f){
  u32 u = __float_as_uint(f);
  u += 0x7fffu + ((u >> 16) & 1u);
  return (u16)(u >> 16);
}
__device__ __forceinline__ u32 pack2(float a, float b){
  return (u32)f2bf(a) | ((u32)f2bf(b) << 16);
}
__device__ __forceinline__ float fast_tanh(float x){
  float e = __expf(2.f*x);
  return 1.f - 2.f*__builtin_amdgcn_rcpf(e + 1.f);
}
__device__ __forceinline__ float fast_sigmoid(float x){
  return __builtin_amdgcn_rcpf(1.f + __expf(-x));
}
__device__ __forceinline__ f32x4 mfma16(s16x8 a, s16x8 b, f32x4 c){
  return __builtin_amdgcn_mfma_f32_16x16x32_bf16(a, b, c, 0, 0, 0);
}
// pack 8 consecutive f32 (two float4) into a bf16x8 fragment, k-order
__device__ __forceinline__ s16x8 packfrag(const float* p){
  const float4 a = *(const float4*)p;
  const float4 b = *(const float4*)(p+4);
  union { s16x8 v; u32 w[4]; } f;
  f.w[0]=pack2(a.x,a.y); f.w[1]=pack2(a.z,a.w);
  f.w[2]=pack2(b.x,b.y); f.w[3]=pack2(b.z,b.w);
  return f.v;
}

// ---------------------------------------------------------------------------
// rnn1 layer 0 via MFMA (unchanged)
// ---------------------------------------------------------------------------
__global__ __launch_bounds__(256) void l0_mfma(
    const float* __restrict__ x,      // (CH,16,128) chunk base
    const float* __restrict__ Wih,    // (2,128,128)
    const float* __restrict__ Whh,    // (2,128,128)
    const float* __restrict__ bih,    // (2,128)
    const float* __restrict__ bhh,    // (2,128)
    u16* __restrict__ out)            // (CH,16,256) bf16
{
  __shared__ __align__(16) u16 Hb[2][32][136];
  __shared__ __align__(16) u16 Xb[2][32][136];
  const int t = threadIdx.x;
  const int lane = t & 63, wv = t >> 6;
  const int l15 = lane & 15, kg = lane >> 4;
  const int dir = blockIdx.y;
  const int f0 = blockIdx.x * 32;
  s16x8 wih[2][4], whh[2][4];
  {
    const float* Wid = Wih + dir*16384;
    const float* Whd = Whh + dir*16384;
    #pragma unroll
    for (int nt = 0; nt < 2; nt++){
      const int u = wv*32 + nt*16 + l15;
      #pragma unroll
      for (int kc = 0; kc < 4; kc++){
        const int k = kc*32 + kg*8;
        wih[nt][kc] = packfrag(&Wid[u*128 + k]);
        whh[nt][kc] = packfrag(&Whd[u*128 + k]);
      }
    }
  }
  float bv[2];
  bv[0] = bih[dir*128 + wv*32 + l15]      + bhh[dir*128 + wv*32 + l15];
  bv[1] = bih[dir*128 + wv*32 + 16 + l15] + bhh[dir*128 + wv*32 + 16 + l15];
  const int sr = t >> 3, sc = (t & 7) * 16;
  {
    *(uint4*)&Hb[0][sr][sc]   = make_uint4(0,0,0,0);
    *(uint4*)&Hb[0][sr][sc+8] = make_uint4(0,0,0,0);
    const int s0 = dir ? 15 : 0;
    const float4* xp = (const float4*)&x[(size_t)(f0+sr)*2048 + s0*128 + sc];
    const float4 v0 = xp[0], v1 = xp[1], v2 = xp[2], v3 = xp[3];
    *(uint4*)&Xb[0][sr][sc]   = make_uint4(pack2(v0.x,v0.y),pack2(v0.z,v0.w),
                                           pack2(v1.x,v1.y),pack2(v1.z,v1.w));
    *(uint4*)&Xb[0][sr][sc+8] = make_uint4(pack2(v2.x,v2.y),pack2(v2.z,v2.w),
                                           pack2(v3.x,v3.y),pack2(v3.z,v3.w));
  }
  __syncthreads();
  int cur = 0;
  for (int st = 0; st < 16; st++){
    const int s = dir ? (15-st) : st;
    float4 p0,p1,p2,p3;
    if (st < 15){
      const int sn = dir ? (14-st) : (st+1);
      const float4* xp = (const float4*)&x[(size_t)(f0+sr)*2048 + sn*128 + sc];
      p0 = xp[0]; p1 = xp[1]; p2 = xp[2]; p3 = xp[3];
    }
    f32x4 acc00 = {0.f,0.f,0.f,0.f}, acc01 = acc00, acc10 = acc00, acc11 = acc00;
    #pragma unroll
    for (int kc = 0; kc < 4; kc++){
      const int ko = kc*32 + kg*8;
      const s16x8 ax0 = *(const s16x8*)&Xb[cur][l15][ko];
      const s16x8 ax1 = *(const s16x8*)&Xb[cur][16+l15][ko];
      const s16x8 ah0 = *(const s16x8*)&Hb[cur][l15][ko];
      const s16x8 ah1 = *(const s16x8*)&Hb[cur][16+l15][ko];
      acc00 = mfma16(ax0, wih[0][kc], acc00);
      acc01 = mfma16(ax0, wih[1][kc], acc01);
      acc10 = mfma16(ax1, wih[0][kc], acc10);
      acc11 = mfma16(ax1, wih[1][kc], acc11);
      acc00 = mfma16(ah0, whh[0][kc], acc00);
      acc01 = mfma16(ah0, whh[1][kc], acc01);
      acc10 = mfma16(ah1, whh[0][kc], acc10);
      acc11 = mfma16(ah1, whh[1][kc], acc11);
    }
    const int u0 = wv*32 + l15, u1 = wv*32 + 16 + l15;
    u16* op = out + (size_t)f0*4096 + s*256 + dir*128;
    #pragma unroll
    for (int r = 0; r < 4; r++){
      const int m0r = kg*4 + r, m1r = 16 + kg*4 + r;
      u16 h00 = f2bf(fast_tanh(acc00[r] + bv[0]));
      u16 h01 = f2bf(fast_tanh(acc01[r] + bv[1]));
      u16 h10 = f2bf(fast_tanh(acc10[r] + bv[0]));
      u16 h11 = f2bf(fast_tanh(acc11[r] + bv[1]));
      Hb[cur^1][m0r][u0] = h00;
      Hb[cur^1][m0r][u1] = h01;
      Hb[cur^1][m1r][u0] = h10;
      Hb[cur^1][m1r][u1] = h11;
      op[(size_t)m0r*4096 + u0] = h00;
      op[(size_t)m0r*4096 + u1] = h01;
      op[(size_t)m1r*4096 + u0] = h10;
      op[(size_t)m1r*4096 + u1] = h11;
    }
    if (st < 15){
      *(uint4*)&Xb[cur^1][sr][sc]   = make_uint4(pack2(p0.x,p0.y),pack2(p0.z,p0.w),
                                                 pack2(p1.x,p1.y),pack2(p1.z,p1.w));
      *(uint4*)&Xb[cur^1][sr][sc+8] = make_uint4(pack2(p2.x,p2.y),pack2(p2.z,p2.w),
                                                 pack2(p3.x,p3.y),pack2(p3.z,p3.w));
    }
    __syncthreads();
    cur ^= 1;
  }
}

// ---------------------------------------------------------------------------
// rnn1 layer 1 FORWARD via MFMA, 16 frames/WG (unchanged)
// ---------------------------------------------------------------------------
__global__ __launch_bounds__(256) void l1f_mfma(
    const u16* __restrict__ U,        // (CH,16,256) bf16
    const float* __restrict__ Wih,    // (2,128,256) dir0
    const float* __restrict__ Whh,    // (2,128,128) dir0
    const float* __restrict__ bih,    // (2,128)
    const float* __restrict__ bhh,
    u16* __restrict__ out)            // rnn1 rows (ld 256), cols 0..127
{
  __shared__ __align__(16) u16 Hb[2][16][136];
  __shared__ __align__(16) u16 Xb[2][16][264];
  const int t = threadIdx.x;
  const int lane = t & 63, wv = t >> 6;
  const int l15 = lane & 15, kg = lane >> 4;
  const int f0 = blockIdx.x * 16;
  s16x8 wih[2][8], whh[2][4];
  {
    #pragma unroll
    for (int nt = 0; nt < 2; nt++){
      const int u = wv*32 + nt*16 + l15;
      #pragma unroll
      for (int kc = 0; kc < 8; kc++)
        wih[nt][kc] = packfrag(&Wih[u*256 + kc*32 + kg*8]);
      #pragma unroll
      for (int kc = 0; kc < 4; kc++)
        whh[nt][kc] = packfrag(&Whh[u*128 + kc*32 + kg*8]);
    }
  }
  float bv[2];
  bv[0] = bih[wv*32 + l15]      + bhh[wv*32 + l15];
  bv[1] = bih[wv*32 + 16 + l15] + bhh[wv*32 + 16 + l15];
  const int sr = t >> 4, scu = (t & 15) * 16;
  for (int idx = t; idx < 272; idx += 256)
    ((uint4*)&Hb[0][0][0])[idx] = make_uint4(0,0,0,0);
  {
    const uint4* up = (const uint4*)&U[(size_t)(f0+sr)*4096 + scu];
    uint4 c0 = up[0], c1 = up[1];
    *(uint4*)&Xb[0][sr][scu]   = c0;
    *(uint4*)&Xb[0][sr][scu+8] = c1;
  }
  __syncthreads();
  int cur = 0;
  for (int st = 0; st < 16; st++){
    uint4 c0,c1;
    if (st < 15){
      const uint4* up = (const uint4*)&U[(size_t)(f0+sr)*4096 + (st+1)*256 + scu];
      c0 = up[0]; c1 = up[1];
    }
    f32x4 acc0 = {0.f,0.f,0.f,0.f}, acc1 = acc0;
    #pragma unroll
    for (int kc = 0; kc < 8; kc++){
      const s16x8 ax = *(const s16x8*)&Xb[cur][l15][kc*32 + kg*8];
      acc0 = mfma16(ax, wih[0][kc], acc0);
      acc1 = mfma16(ax, wih[1][kc], acc1);
    }
    #pragma unroll
    for (int kc = 0; kc < 4; kc++){
      const s16x8 ah = *(const s16x8*)&Hb[cur][l15][kc*32 + kg*8];
      acc0 = mfma16(ah, whh[0][kc], acc0);
      acc1 = mfma16(ah, whh[1][kc], acc1);
    }
    const int u0 = wv*32 + l15, u1 = wv*32 + 16 + l15;
    #pragma unroll
    for (int r = 0; r < 4; r++){
      const int m = kg*4 + r;
      const u16 h0 = f2bf(fast_tanh(acc0[r] + bv[0]));
      const u16 h1 = f2bf(fast_tanh(acc1[r] + bv[1]));
      Hb[cur^1][m][u0] = h0;
      Hb[cur^1][m][u1] = h1;
      if (st == 15){
        out[(size_t)(f0+m)*256 + u0] = h0;
        out[(size_t)(f0+m)*256 + u1] = h1;
      }
    }
    if (st < 15){
      *(uint4*)&Xb[cur^1][sr][scu]   = c0;
      *(uint4*)&Xb[cur^1][sr][scu+8] = c1;
    }
    __syncthreads();
    cur ^= 1;
  }
}

// ---------------------------------------------------------------------------
// Register-only MFMA GEMM: C(M,N) = A @ Wb^T + bias [tanh], bf16/f32 out.
// ---------------------------------------------------------------------------
__global__ __launch_bounds__(256) void mfma_gemm(
    const u16* __restrict__ A, int lda,
    const u16* __restrict__ Wb, int K,
    const float* __restrict__ bias,
    float* __restrict__ Cf, u16* __restrict__ Cb, int ldc, int act)
{
  const int t = threadIdx.x;
  const int lane = t & 63, wv = t >> 6;
  const int l15 = lane & 15, kg = lane >> 4;
  const int n0 = blockIdx.x * 32;
  const int m0 = blockIdx.y * 64 + wv*16;
  const u16* Ap = A + (size_t)(m0 + l15)*lda + kg*8;
  const u16* W0 = Wb + (size_t)(n0 + l15)*K + kg*8;
  const u16* W1 = Wb + (size_t)(n0 + 16 + l15)*K + kg*8;
  f32x4 acc0 = {0.f,0.f,0.f,0.f}, acc1 = acc0;
  #pragma unroll 4
  for (int kc = 0; kc < K/32; kc++){
    const s16x8 a  = *(const s16x8*)(Ap + kc*32);
    const s16x8 b0 = *(const s16x8*)(W0 + kc*32);
    const s16x8 b1 = *(const s16x8*)(W1 + kc*32);
    acc0 = mfma16(a, b0, acc0);
    acc1 = mfma16(a, b1, acc1);
  }
  const int col0 = n0 + l15, col1 = n0 + 16 + l15;
  const float bv0 = bias[col0], bv1 = bias[col1];
  #pragma unroll
  for (int r = 0; r < 4; r++){
    const int row = m0 + kg*4 + r;
    float v0 = acc0[r] + bv0, v1 = acc1[r] + bv1;
    if (act){ v0 = fast_tanh(v0); v1 = fast_tanh(v1); }
    if (Cf){
      Cf[(size_t)row*ldc + col0] = v0;
      Cf[(size_t)row*ldc + col1] = v1;
    } else {
      Cb[(size_t)row*ldc + col0] = f2bf(v0);
      Cb[(size_t)row*ldc + col1] = f2bf(v1);
    }
  }
}

// ---------------------------------------------------------------------------
// xw GEMM -> gru-native v2 layout (for operand-swapped gru):
// idx = (((((d*512+tt)*2 + half)*4 + w)*4 + kgu)*16 + bl)*24 + t*12 + g*4 + ru
// where col -> d,g,cu; cu = (w*32 + t*16 + kgu*4 + ru); row -> b,tt;
// b -> half*16 + bl.  Each gru lane's 24 floats are contiguous (96B).
// bhh is folded in for r,z gates only (n-gate bhh stays separate in gru).
// ---------------------------------------------------------------------------
__global__ __launch_bounds__(256) void gemm_xw(
    const u16* __restrict__ A, int lda,
    const u16* __restrict__ Wb, int K,
    const float* __restrict__ bih, const float* __restrict__ bhhp,
    float* __restrict__ xwT)
{
  const int t = threadIdx.x;
  const int lane = t & 63, wv = t >> 6;
  const int l15 = lane & 15, kg = lane >> 4;
  const int n0 = blockIdx.x * 32;
  const int m0 = blockIdx.y * 64 + wv*16;
  const u16* Ap = A + (size_t)(m0 + l15)*lda + kg*8;
  const u16* W0 = Wb + (size_t)(n0 + l15)*K + kg*8;
  const u16* W1 = Wb + (size_t)(n0 + 16 + l15)*K + kg*8;
  f32x4 acc0 = {0.f,0.f,0.f,0.f}, acc1 = acc0;
  #pragma unroll 4
  for (int kc = 0; kc < K/32; kc++){
    const s16x8 a  = *(const s16x8*)(Ap + kc*32);
    const s16x8 b0 = *(const s16x8*)(W0 + kc*32);
    const s16x8 b1 = *(const s16x8*)(W1 + kc*32);
    acc0 = mfma16(a, b0, acc0);
    acc1 = mfma16(a, b1, acc1);
  }
  const int col0 = n0 + l15, col1 = n0 + 16 + l15;
  const int row0 = m0 + kg*4;
  const int b = row0 >> 9, tt0 = row0 & 511;
  const int half = b >> 4, bl = b & 15;
  float bv0 = bih[col0], bv1 = bih[col1];
  {
    const int c0 = col0 >= 384 ? col0-384 : col0;
    const int c1 = col1 >= 384 ? col1-384 : col1;
    if ((c0 >> 7) < 2) bv0 += bhhp[col0];
    if ((c1 >> 7) < 2) bv1 += bhhp[col1];
  }
  size_t i0, i1;
  {
    const int d0 = col0 >= 384 ? 1 : 0;
    const int c  = col0 - d0*384;
    const int g = c >> 7, cu = c & 127;
    i0 = (((((size_t)d0*512 + tt0)*2 + half)*4 + (cu>>5))*4 + ((cu>>2)&3))*384
         + (size_t)bl*24 + ((cu>>4)&1)*12 + g*4 + (cu&3);
  }
  {
    const int d1 = col1 >= 384 ? 1 : 0;
    const int c  = col1 - d1*384;
    const int g = c >> 7, cu = c & 127;
    i1 = (((((size_t)d1*512 + tt0)*2 + half)*4 + (cu>>5))*4 + ((cu>>2)&3))*384
         + (size_t)bl*24 + ((cu>>4)&1)*12 + g*4 + (cu&3);
  }
  #pragma unroll
  for (int r = 0; r < 4; r++){
    xwT[i0 + (size_t)r*12288] = acc0[r] + bv0;
    xwT[i1 + (size_t)r*12288] = acc1[r] + bv1;
  }
}

// ---------------------------------------------------------------------------
// Weight prep (unchanged).
// ---------------------------------------------------------------------------
__global__ __launch_bounds__(256) void prep_kernel(
    const float* __restrict__ g0W, const float* __restrict__ g1W,
    const float* __restrict__ r1Wih,
    const float* __restrict__ r1bih, const float* __restrict__ r1bhh,
    u16* __restrict__ g0o, u16* __restrict__ g1o, u16* __restrict__ r1o,
    float* __restrict__ bo)
{
  const int i = blockIdx.x*256 + threadIdx.x;
  if (i < 196608){ g0o[i] = f2bf(g0W[i]); g1o[i] = f2bf(g1W[i]); }
  if (i < 32768)   r1o[i] = f2bf(r1Wih[32768 + i]);
  if (i < 128)     bo[i]  = r1bih[128+i] + r1bhh[128+i];
}

// ---------------------------------------------------------------------------
// Operand-swapped batched-MFMA GRU. 4 WGs (dir, half) x 4 waves (256 thr).
// Computes G^T(384,16) = Whh @ H^T: A = Whh frags (regs), B = h frag (LDS).
// Wave w owns gate-units [32w,32w+32) for all 3 gates (6 tile-gate chains,
// 24 MFMAs). D: row = unit, col = batch -> lane holds 8 (batch,unit) h's at
// 2 runs of 4 consecutive units: LDS write = 2 x b64, hout = 2 x 8B stores.
// h reads: 4 x ds_read_b128 per wave (16/CU/step). One barrier per step.
// ---------------------------------------------------------------------------
__global__ __launch_bounds__(256, 1) void gru_mfma(
    const float* __restrict__ xwT,  // (2,512,12288) gru-native v2
    const float* __restrict__ Whh,  // (2,384,128) f32
    const float* __restrict__ bhh,  // (2,384)
    u16* __restrict__ hout)         // (16384,256) bf16
{
  __shared__ __align__(16) u16 h_lds[2][16][136];
  const int t = threadIdx.x;
  const int lane = t & 63, wv = t >> 6;
  const int l15 = lane & 15, kg = lane >> 4;
  const int dir = blockIdx.x & 1, half = blockIdx.x >> 1;
  // Whh A-fragments: [tile t2][gate g][kc]; row = g*128 + wv*32 + t2*16 + l15
  s16x8 wa[2][3][4];
  {
    const float* Wd = Whh + (size_t)dir*49152;
    #pragma unroll
    for (int t2 = 0; t2 < 2; t2++)
      #pragma unroll
      for (int g = 0; g < 3; g++)
        #pragma unroll
        for (int kc = 0; kc < 4; kc++)
          wa[t2][g][kc] = packfrag(&Wd[(size_t)(g*128 + wv*32 + t2*16 + l15)*128
                                       + kc*32 + kg*8]);
  }
  f32x4 bhn[2];
  bhn[0] = *(const f32x4*)&bhh[dir*384 + 256 + wv*32 + kg*4];
  bhn[1] = *(const f32x4*)&bhh[dir*384 + 256 + wv*32 + 16 + kg*4];
  // zero h buffer 0 (272 uint4)
  {
    const uint4 z = make_uint4(0,0,0,0);
    ((uint4*)h_lds)[t] = z;
    if (t < 16) ((uint4*)h_lds)[256 + t] = z;
  }
  f32x4 hreg[2] = {{0.f,0.f,0.f,0.f},{0.f,0.f,0.f,0.f}};
  const long tstep = dir ? -49152L : 49152L;     // bytes per tt step
  const char* xb = (const char*)xwT
      + ((size_t)dir*512 + (dir ? 511 : 0))*49152
      + (size_t)((((half*4 + wv)*4 + kg)*16 + l15)*24)*4;
  f32x4 pa[6], pb[6];
  #pragma unroll
  for (int j = 0; j < 6; j++) pa[j] = *(const f32x4*)(xb + j*16);
  xb += tstep;
  #pragma unroll
  for (int j = 0; j < 6; j++) pb[j] = *(const f32x4*)(xb + j*16);
  xb += tstep;
  const int hstep = dir ? -256 : 256;            // u16 units per tt step
  int hoff = ((half*16 + l15)*512 + (dir ? 511 : 0))*256 + dir*128 + wv*32 + kg*4;
  __syncthreads();
  int cur = 0;

#define GSTEP(PX, DOLOAD)                                                   \
  {                                                                         \
    f32x4 acc[2][3] = {{{0.f,0.f,0.f,0.f},{0.f,0.f,0.f,0.f},               \
                        {0.f,0.f,0.f,0.f}},                                 \
                       {{0.f,0.f,0.f,0.f},{0.f,0.f,0.f,0.f},               \
                        {0.f,0.f,0.f,0.f}}};                                \
    _Pragma("unroll")                                                       \
    for (int kc = 0; kc < 4; kc++){                                         \
      const s16x8 hf = *(const s16x8*)&h_lds[cur][l15][kc*32 + kg*8];       \
      _Pragma("unroll")                                                     \
      for (int t2 = 0; t2 < 2; t2++)                                        \
        _Pragma("unroll")                                                   \
        for (int g = 0; g < 3; g++)                                         \
          acc[t2][g] = mfma16(wa[t2][g][kc], hf, acc[t2][g]);               \
    }                                                                       \
    f32x4 nx0,nx1,nx2,nx3,nx4,nx5;                                          \
    if (DOLOAD){                                                            \
      nx0 = *(const f32x4*)(xb);     nx1 = *(const f32x4*)(xb+16);          \
      nx2 = *(const f32x4*)(xb+32);  nx3 = *(const f32x4*)(xb+48);          \
      nx4 = *(const f32x4*)(xb+64);  nx5 = *(const f32x4*)(xb+80);          \
      xb += tstep;                                                          \
    }                                                                       \
    _Pragma("unroll")                                                       \
    for (int t2 = 0; t2 < 2; t2++){                                         \
      float hn[4];                                                          \
      _Pragma("unroll")                                                     \
      for (int r = 0; r < 4; r++){                                          \
        const float rr = fast_sigmoid(PX[t2*3+0][r] + acc[t2][0][r]);       \
        const float zz = fast_sigmoid(PX[t2*3+1][r] + acc[t2][1][r]);       \
        const float nn = fast_tanh(PX[t2*3+2][r]                            \
                                   + rr*(acc[t2][2][r] + bhn[t2][r]));      \
        hn[r] = fmaf(zz, hreg[t2][r] - nn, nn);                             \
        hreg[t2][r] = hn[r];                                                \
      }                                                                     \
      const uint2 hp = make_uint2(pack2(hn[0],hn[1]), pack2(hn[2],hn[3]));  \
      *(uint2*)&h_lds[cur^1][l15][wv*32 + t2*16 + kg*4] = hp;               \
      *(uint2*)&hout[hoff + t2*16] = hp;                                    \
    }                                                                       \
    hoff += hstep;                                                          \
    if (DOLOAD){                                                            \
      PX[0]=nx0; PX[1]=nx1; PX[2]=nx2; PX[3]=nx3; PX[4]=nx4; PX[5]=nx5;     \
    }                                                                       \
    __syncthreads();                                                        \
    cur ^= 1;                                                               \
  }

  for (int ti = 0; ti < 510; ti += 2){
    GSTEP(pa, 1);
    GSTEP(pb, 1);
  }
  GSTEP(pa, 0);   // step 510: no prefetch (would run past tt range)
  GSTEP(pb, 0);   // step 511
#undef GSTEP
}

__global__ void prefix_kernel(const int* __restrict__ lengths, int* __restrict__ pre){
  if (threadIdx.x == 0 && blockIdx.x == 0){
    int run = 0;
    for (int b = 0; b < 32; b++){ pre[b] = run; run += lengths[b]; }
  }
}

// ---------------------------------------------------------------------------
// Final FC (61 x 256) + ragged masked scatter into d_out (unchanged).
// ---------------------------------------------------------------------------
__global__ __launch_bounds__(256) void fc_kernel(
    const u16* __restrict__ A,      // (16384,256) bf16
    const float* __restrict__ W,    // (61,256)
    const float* __restrict__ bias, // (61)
    const int* __restrict__ lengths,
    const int* __restrict__ pre,
    float* __restrict__ out)
{
  __shared__ __align__(16) float4 Wl[64][61];
  __shared__ __align__(16) float  Al[64][256];
  const int t = threadIdx.x;
  const int row0 = blockIdx.x * 64;
  for (int idx = t; idx < 61*64; idx += 256){
    int c = idx >> 6, k4 = idx & 63;
    Wl[k4][c] = *(const float4*)&W[(size_t)c*256 + k4*4];
  }
  {
    const u32* A32 = (const u32*)(A + (size_t)row0*256);
    for (int idx = t; idx < 8192; idx += 256){
      u32 v = A32[idx];
      int r = idx >> 7, kp = idx & 127;
      Al[r][2*kp]   = bflo(v);
      Al[r][2*kp+1] = bfhi(v);
    }
  }
  __syncthreads();
  const int c = t & 63;
  const int rbase = t >> 6;
  if (c < 61){
    const float bv = bias[c];
    for (int rr = rbase; rr < 64; rr += 4){
      float s0=0,s1=0,s2=0,s3=0;
      const float4* Ap = (const float4*)&Al[rr][0];
      #pragma unroll
      for (int k4 = 0; k4 < 64; k4++){
        const float4 w = Wl[k4][c];
        const float4 a = Ap[k4];
        s0 = fmaf(w.x, a.x, s0);
        s1 = fmaf(w.y, a.y, s1);
        s2 = fmaf(w.z, a.z, s2);
        s3 = fmaf(w.w, a.w, s3);
      }
      const int n = row0 + rr;
      const int b = n >> 9, tt = n & 511;
      if (tt < lengths[b])
        out[(size_t)(pre[b] + tt)*61 + c] = bv + s0+s1+s2+s3;
    }
  }
}

extern "C" void kernel_launch(void* const* d_in, const int* in_sizes, int n_in,
                              void* d_out, int out_size, void* d_ws, size_t ws_size,
                              hipStream_t stream)
{
  const float* x     = (const float*)d_in[0];
  const int*   lens  = (const int*)d_in[1];
  const float* r0Wih = (const float*)d_in[2];
  const float* r0Whh = (const float*)d_in[3];
  const float* r0bih = (const float*)d_in[4];
  const float* r0bhh = (const float*)d_in[5];
  const float* r1Wih = (const float*)d_in[6];
  const float* r1Whh = (const float*)d_in[7];
  const float* r1bih = (const float*)d_in[8];
  const float* r1bhh = (const float*)d_in[9];
  const float* g0Wih = (const float*)d_in[10];
  const float* g0Whh = (const float*)d_in[11];
  const float* g0bih = (const float*)d_in[12];
  const float* g0bhh = (const float*)d_in[13];
  const float* g1Wih = (const float*)d_in[14];
  const float* g1Whh = (const float*)d_in[15];
  const float* g1bih = (const float*)d_in[16];
  const float* g1bhh = (const float*)d_in[17];
  const float* fcW   = (const float*)d_in[18];
  const float* fcb   = (const float*)d_in[19];
  float* out = (float*)d_out;

  char* ws = (char*)d_ws;
  u16*   l0buf = (u16*)(ws);
  float* xwbuf = (float*)(ws);                      // xwT (2,512,12288) f32
  u16*   g0out = (u16*)(ws + 50331648);
  u16*   g0Wb  = (u16*)(ws + 58720256);             // 393216 B
  u16*   g1Wb  = (u16*)(ws + 58720256 + 393216);    // 393216 B
  u16*   r1Wb  = (u16*)(ws + 58720256 + 786432);    // 65536 B
  float* biasb = (float*)(ws + 58720256 + 851968);  // 512 B
  u16*   g1out = (u16*)(ws + 58720256);             // overwrites prep late
  u16*   rnn1  = (u16*)(ws + 67108864);
  int*   pre   = (int*)(ws + 75497472);

  prep_kernel<<<768, 256, 0, stream>>>(g0Wih, g1Wih, r1Wih, r1bih, r1bhh,
                                       g0Wb, g1Wb, r1Wb, biasb);
  for (int c = 0; c < NF_/CH_; c++){
    l0_mfma<<<dim3(CH_/32, 2), 256, 0, stream>>>(
        x + (size_t)c*CH_*2048, r0Wih, r0Whh, r0bih, r0bhh, l0buf);
    l1f_mfma<<<dim3(CH_/16), 256, 0, stream>>>(
        l0buf, r1Wih, r1Whh, r1bih, r1bhh, rnn1 + (size_t)c*CH_*256);
    mfma_gemm<<<dim3(128/32, CH_/64), 256, 0, stream>>>(
        l0buf + 15*256, 4096, r1Wb, 256, biasb,
        (float*)nullptr, rnn1 + (size_t)c*CH_*256 + 128, 256, 1);
  }
  // GRU layer 0
  gemm_xw<<<dim3(768/32, NF_/64), 256, 0, stream>>>(
      rnn1, 256, g0Wb, 256, g0bih, g0bhh, xwbuf);
  gru_mfma<<<4, 256, 0, stream>>>(xwbuf, g0Whh, g0bhh, g0out);
  // GRU layer 1
  gemm_xw<<<dim3(768/32, NF_/64), 256, 0, stream>>>(
      g0out, 256, g1Wb, 256, g1bih, g1bhh, xwbuf);
  gru_mfma<<<4, 256, 0, stream>>>(xwbuf, g1Whh, g1bhh, g1out);
  // FC + ragged scatter
  prefix_kernel<<<1, 64, 0, stream>>>(lens, pre);
  fc_kernel<<<NF_/64, 256, 0, stream>>>(g1out, fcW, fcb, lens, pre, out);
}

// Round 7
// 1033.164 us; speedup vs baseline: 1.1523x; 1.1523x over previous
//
#include <hip/hip_runtime.h>
#include <hip/hip_bf16.h>

#define B_ 32
#define T_ 512
#define L_ 16
#define F_ 128
#define H_ 128
#define C_ 61
#define NF_ (B_*T_)   // 16384 frames
#define CH_ 4096      // frames per rnn1 chunk

typedef unsigned int u32;
typedef unsigned short u16;
typedef __attribute__((ext_vector_type(8))) short s16x8;
typedef __attribute__((ext_vector_type(4))) float f32x4;

__device__ __forceinline__ float bflo(u32 v){ return __uint_as_float(v << 16); }
__device__ __forceinline__ float bfhi(u32 v){ return __uint_as_float(v & 0xffff0000u); }
__device__ __forceinline__ u16 f2bf(float f){
  u32 u = __float_as_uint(f);
  u += 0x7fffu + ((u >> 16) & 1u);
  return (u16)(u >> 16);
}
__device__ __forceinline__ u32 pack2(float a, float b){
  return (u32)f2bf(a) | ((u32)f2bf(b) << 16);
}
__device__ __forceinline__ float fast_tanh(float x){
  float e = __expf(2.f*x);
  return 1.f - 2.f*__builtin_amdgcn_rcpf(e + 1.f);
}
__device__ __forceinline__ float fast_sigmoid(float x){
  return __builtin_amdgcn_rcpf(1.f + __expf(-x));
}
__device__ __forceinline__ f32x4 mfma16(s16x8 a, s16x8 b, f32x4 c){
  return __builtin_amdgcn_mfma_f32_16x16x32_bf16(a, b, c, 0, 0, 0);
}
// LDS-only barrier: does NOT drain vmcnt, so global prefetch loads and
// fire-and-forget stores stay in flight across steps (unlike __syncthreads,
// which the compiler lowers with a full vmcnt(0) drain).
__device__ __forceinline__ void lds_barrier(){
  asm volatile("s_waitcnt lgkmcnt(0)\n\ts_barrier" ::: "memory");
}
// pack 8 consecutive f32 (two float4) into a bf16x8 fragment, k-order
__device__ __forceinline__ s16x8 packfrag(const float* p){
  const float4 a = *(const float4*)p;
  const float4 b = *(const float4*)(p+4);
  union { s16x8 v; u32 w[4]; } f;
  f.w[0]=pack2(a.x,a.y); f.w[1]=pack2(a.z,a.w);
  f.w[2]=pack2(b.x,b.y); f.w[3]=pack2(b.z,b.w);
  return f.v;
}

// ---------------------------------------------------------------------------
// rnn1 layer 0 via MFMA. Now 16 frames/WG (grid CH/16 x 2 = 512 WGs -> 2/CU).
// Per step: acc = X_s@Wih^T + H@Whh^T, tanh, H to LDS + out. LDS-only barrier.
// ---------------------------------------------------------------------------
__global__ __launch_bounds__(256) void l0_mfma(
    const float* __restrict__ x,      // (CH,16,128) chunk base
    const float* __restrict__ Wih,    // (2,128,128)
    const float* __restrict__ Whh,    // (2,128,128)
    const float* __restrict__ bih,    // (2,128)
    const float* __restrict__ bhh,    // (2,128)
    u16* __restrict__ out)            // (CH,16,256) bf16
{
  __shared__ __align__(16) u16 Hb[2][16][136];
  __shared__ __align__(16) u16 Xb[2][16][136];
  const int t = threadIdx.x;
  const int lane = t & 63, wv = t >> 6;
  const int l15 = lane & 15, kg = lane >> 4;
  const int dir = blockIdx.y;
  const int f0 = blockIdx.x * 16;
  s16x8 wih[2][4], whh[2][4];
  {
    const float* Wid = Wih + dir*16384;
    const float* Whd = Whh + dir*16384;
    #pragma unroll
    for (int nt = 0; nt < 2; nt++){
      const int u = wv*32 + nt*16 + l15;
      #pragma unroll
      for (int kc = 0; kc < 4; kc++){
        const int k = kc*32 + kg*8;
        wih[nt][kc] = packfrag(&Wid[u*128 + k]);
        whh[nt][kc] = packfrag(&Whd[u*128 + k]);
      }
    }
  }
  float bv[2];
  bv[0] = bih[dir*128 + wv*32 + l15]      + bhh[dir*128 + wv*32 + l15];
  bv[1] = bih[dir*128 + wv*32 + 16 + l15] + bhh[dir*128 + wv*32 + 16 + l15];
  const int sr = t >> 4, sc8 = (t & 15) * 8;   // stage: frame row, col (8 f32)
  for (int idx = t; idx < 272; idx += 256)
    ((uint4*)&Hb[0][0][0])[idx] = make_uint4(0,0,0,0);
  {
    const int s0 = dir ? 15 : 0;
    const float4* xp = (const float4*)&x[(size_t)(f0+sr)*2048 + s0*128 + sc8];
    const float4 v0 = xp[0], v1 = xp[1];
    *(uint4*)&Xb[0][sr][sc8] = make_uint4(pack2(v0.x,v0.y),pack2(v0.z,v0.w),
                                          pack2(v1.x,v1.y),pack2(v1.z,v1.w));
  }
  lds_barrier();
  int cur = 0;
  for (int st = 0; st < 16; st++){
    const int s = dir ? (15-st) : st;
    float4 p0,p1;
    if (st < 15){
      const int sn = dir ? (14-st) : (st+1);
      const float4* xp = (const float4*)&x[(size_t)(f0+sr)*2048 + sn*128 + sc8];
      p0 = xp[0]; p1 = xp[1];
    }
    f32x4 acc0 = {0.f,0.f,0.f,0.f}, acc1 = acc0;
    #pragma unroll
    for (int kc = 0; kc < 4; kc++){
      const int ko = kc*32 + kg*8;
      const s16x8 ax = *(const s16x8*)&Xb[cur][l15][ko];
      const s16x8 ah = *(const s16x8*)&Hb[cur][l15][ko];
      acc0 = mfma16(ax, wih[0][kc], acc0);
      acc1 = mfma16(ax, wih[1][kc], acc1);
      acc0 = mfma16(ah, whh[0][kc], acc0);
      acc1 = mfma16(ah, whh[1][kc], acc1);
    }
    const int u0 = wv*32 + l15, u1 = wv*32 + 16 + l15;
    u16* op = out + (size_t)f0*4096 + s*256 + dir*128;
    #pragma unroll
    for (int r = 0; r < 4; r++){
      const int m = kg*4 + r;
      const u16 h0 = f2bf(fast_tanh(acc0[r] + bv[0]));
      const u16 h1 = f2bf(fast_tanh(acc1[r] + bv[1]));
      Hb[cur^1][m][u0] = h0;
      Hb[cur^1][m][u1] = h1;
      op[(size_t)m*4096 + u0] = h0;
      op[(size_t)m*4096 + u1] = h1;
    }
    if (st < 15){
      *(uint4*)&Xb[cur^1][sr][sc8] = make_uint4(pack2(p0.x,p0.y),pack2(p0.z,p0.w),
                                                pack2(p1.x,p1.y),pack2(p1.z,p1.w));
    }
    lds_barrier();
    cur ^= 1;
  }
}

// ---------------------------------------------------------------------------
// rnn1 layer 1 FORWARD via MFMA, 16 frames/WG (LDS-only barriers).
// ---------------------------------------------------------------------------
__global__ __launch_bounds__(256) void l1f_mfma(
    const u16* __restrict__ U,        // (CH,16,256) bf16
    const float* __restrict__ Wih,    // (2,128,256) dir0
    const float* __restrict__ Whh,    // (2,128,128) dir0
    const float* __restrict__ bih,    // (2,128)
    const float* __restrict__ bhh,
    u16* __restrict__ out)            // rnn1 rows (ld 256), cols 0..127
{
  __shared__ __align__(16) u16 Hb[2][16][136];
  __shared__ __align__(16) u16 Xb[2][16][264];
  const int t = threadIdx.x;
  const int lane = t & 63, wv = t >> 6;
  const int l15 = lane & 15, kg = lane >> 4;
  const int f0 = blockIdx.x * 16;
  s16x8 wih[2][8], whh[2][4];
  {
    #pragma unroll
    for (int nt = 0; nt < 2; nt++){
      const int u = wv*32 + nt*16 + l15;
      #pragma unroll
      for (int kc = 0; kc < 8; kc++)
        wih[nt][kc] = packfrag(&Wih[u*256 + kc*32 + kg*8]);
      #pragma unroll
      for (int kc = 0; kc < 4; kc++)
        whh[nt][kc] = packfrag(&Whh[u*128 + kc*32 + kg*8]);
    }
  }
  float bv[2];
  bv[0] = bih[wv*32 + l15]      + bhh[wv*32 + l15];
  bv[1] = bih[wv*32 + 16 + l15] + bhh[wv*32 + 16 + l15];
  const int sr = t >> 4, scu = (t & 15) * 16;
  for (int idx = t; idx < 272; idx += 256)
    ((uint4*)&Hb[0][0][0])[idx] = make_uint4(0,0,0,0);
  {
    const uint4* up = (const uint4*)&U[(size_t)(f0+sr)*4096 + scu];
    uint4 c0 = up[0], c1 = up[1];
    *(uint4*)&Xb[0][sr][scu]   = c0;
    *(uint4*)&Xb[0][sr][scu+8] = c1;
  }
  lds_barrier();
  int cur = 0;
  for (int st = 0; st < 16; st++){
    uint4 c0,c1;
    if (st < 15){
      const uint4* up = (const uint4*)&U[(size_t)(f0+sr)*4096 + (st+1)*256 + scu];
      c0 = up[0]; c1 = up[1];
    }
    f32x4 acc0 = {0.f,0.f,0.f,0.f}, acc1 = acc0;
    #pragma unroll
    for (int kc = 0; kc < 8; kc++){
      const s16x8 ax = *(const s16x8*)&Xb[cur][l15][kc*32 + kg*8];
      acc0 = mfma16(ax, wih[0][kc], acc0);
      acc1 = mfma16(ax, wih[1][kc], acc1);
    }
    #pragma unroll
    for (int kc = 0; kc < 4; kc++){
      const s16x8 ah = *(const s16x8*)&Hb[cur][l15][kc*32 + kg*8];
      acc0 = mfma16(ah, whh[0][kc], acc0);
      acc1 = mfma16(ah, whh[1][kc], acc1);
    }
    const int u0 = wv*32 + l15, u1 = wv*32 + 16 + l15;
    #pragma unroll
    for (int r = 0; r < 4; r++){
      const int m = kg*4 + r;
      const u16 h0 = f2bf(fast_tanh(acc0[r] + bv[0]));
      const u16 h1 = f2bf(fast_tanh(acc1[r] + bv[1]));
      Hb[cur^1][m][u0] = h0;
      Hb[cur^1][m][u1] = h1;
      if (st == 15){
        out[(size_t)(f0+m)*256 + u0] = h0;
        out[(size_t)(f0+m)*256 + u1] = h1;
      }
    }
    if (st < 15){
      *(uint4*)&Xb[cur^1][sr][scu]   = c0;
      *(uint4*)&Xb[cur^1][sr][scu+8] = c1;
    }
    lds_barrier();
    cur ^= 1;
  }
}

// ---------------------------------------------------------------------------
// Register-only MFMA GEMM: C(M,N) = A @ Wb^T + bias [tanh], bf16/f32 out.
// ---------------------------------------------------------------------------
__global__ __launch_bounds__(256) void mfma_gemm(
    const u16* __restrict__ A, int lda,
    const u16* __restrict__ Wb, int K,
    const float* __restrict__ bias,
    float* __restrict__ Cf, u16* __restrict__ Cb, int ldc, int act)
{
  const int t = threadIdx.x;
  const int lane = t & 63, wv = t >> 6;
  const int l15 = lane & 15, kg = lane >> 4;
  const int n0 = blockIdx.x * 32;
  const int m0 = blockIdx.y * 64 + wv*16;
  const u16* Ap = A + (size_t)(m0 + l15)*lda + kg*8;
  const u16* W0 = Wb + (size_t)(n0 + l15)*K + kg*8;
  const u16* W1 = Wb + (size_t)(n0 + 16 + l15)*K + kg*8;
  f32x4 acc0 = {0.f,0.f,0.f,0.f}, acc1 = acc0;
  #pragma unroll 4
  for (int kc = 0; kc < K/32; kc++){
    const s16x8 a  = *(const s16x8*)(Ap + kc*32);
    const s16x8 b0 = *(const s16x8*)(W0 + kc*32);
    const s16x8 b1 = *(const s16x8*)(W1 + kc*32);
    acc0 = mfma16(a, b0, acc0);
    acc1 = mfma16(a, b1, acc1);
  }
  const int col0 = n0 + l15, col1 = n0 + 16 + l15;
  const float bv0 = bias[col0], bv1 = bias[col1];
  #pragma unroll
  for (int r = 0; r < 4; r++){
    const int row = m0 + kg*4 + r;
    float v0 = acc0[r] + bv0, v1 = acc1[r] + bv1;
    if (act){ v0 = fast_tanh(v0); v1 = fast_tanh(v1); }
    if (Cf){
      Cf[(size_t)row*ldc + col0] = v0;
      Cf[(size_t)row*ldc + col1] = v1;
    } else {
      Cb[(size_t)row*ldc + col0] = f2bf(v0);
      Cb[(size_t)row*ldc + col1] = f2bf(v1);
    }
  }
}

// ---------------------------------------------------------------------------
// xw GEMM -> gru-native v3 layout: per (d,tt,half) block of 6144 floats,
// lane (wv,kg,l15) owns 12 contiguous floats at ((wv*4+kg)*16+l15)*12,
// ordered g*4+r for unit u = wv*16+kg*4+r.  bih+bhh folded for r,z gates.
// ---------------------------------------------------------------------------
__global__ __launch_bounds__(256) void gemm_xw(
    const u16* __restrict__ A, int lda,
    const u16* __restrict__ Wb, int K,
    const float* __restrict__ bih, const float* __restrict__ bhhp,
    float* __restrict__ xwT)
{
  const int t = threadIdx.x;
  const int lane = t & 63, wv = t >> 6;
  const int l15 = lane & 15, kg = lane >> 4;
  const int n0 = blockIdx.x * 32;
  const int m0 = blockIdx.y * 64 + wv*16;
  const u16* Ap = A + (size_t)(m0 + l15)*lda + kg*8;
  const u16* W0 = Wb + (size_t)(n0 + l15)*K + kg*8;
  const u16* W1 = Wb + (size_t)(n0 + 16 + l15)*K + kg*8;
  f32x4 acc0 = {0.f,0.f,0.f,0.f}, acc1 = acc0;
  #pragma unroll 4
  for (int kc = 0; kc < K/32; kc++){
    const s16x8 a  = *(const s16x8*)(Ap + kc*32);
    const s16x8 b0 = *(const s16x8*)(W0 + kc*32);
    const s16x8 b1 = *(const s16x8*)(W1 + kc*32);
    acc0 = mfma16(a, b0, acc0);
    acc1 = mfma16(a, b1, acc1);
  }
  const int col0 = n0 + l15, col1 = n0 + 16 + l15;
  const int row0 = m0 + kg*4;
  const int b = row0 >> 9, tt0 = row0 & 511;
  const int half = b >> 4, bl = b & 15;
  float bv0 = bih[col0], bv1 = bih[col1];
  {
    const int c0 = col0 >= 384 ? col0-384 : col0;
    const int c1 = col1 >= 384 ? col1-384 : col1;
    if ((c0 >> 7) < 2) bv0 += bhhp[col0];
    if ((c1 >> 7) < 2) bv1 += bhhp[col1];
  }
  size_t i0, i1;
  {
    const int d0 = col0 >= 384 ? 1 : 0;
    const int c  = col0 - d0*384;
    const int g = c >> 7, cu = c & 127;
    i0 = (((size_t)d0*512 + tt0)*2 + half)*6144
         + (size_t)(((cu>>4)*4 + ((cu>>2)&3))*16 + bl)*12 + g*4 + (cu&3);
  }
  {
    const int d1 = col1 >= 384 ? 1 : 0;
    const int c  = col1 - d1*384;
    const int g = c >> 7, cu = c & 127;
    i1 = (((size_t)d1*512 + tt0)*2 + half)*6144
         + (size_t)(((cu>>4)*4 + ((cu>>2)&3))*16 + bl)*12 + g*4 + (cu&3);
  }
  #pragma unroll
  for (int r = 0; r < 4; r++){
    xwT[i0 + (size_t)r*12288] = acc0[r] + bv0;
    xwT[i1 + (size_t)r*12288] = acc1[r] + bv1;
  }
}

// ---------------------------------------------------------------------------
// Weight prep (unchanged).
// ---------------------------------------------------------------------------
__global__ __launch_bounds__(256) void prep_kernel(
    const float* __restrict__ g0W, const float* __restrict__ g1W,
    const float* __restrict__ r1Wih,
    const float* __restrict__ r1bih, const float* __restrict__ r1bhh,
    u16* __restrict__ g0o, u16* __restrict__ g1o, u16* __restrict__ r1o,
    float* __restrict__ bo)
{
  const int i = blockIdx.x*256 + threadIdx.x;
  if (i < 196608){ g0o[i] = f2bf(g0W[i]); g1o[i] = f2bf(g1W[i]); }
  if (i < 32768)   r1o[i] = f2bf(r1Wih[32768 + i]);
  if (i < 128)     bo[i]  = r1bih[128+i] + r1bhh[128+i];
}

// ---------------------------------------------------------------------------
// GRU scan v3. 4 WGs (dir, half) x 8 waves (512 thr). Wave w owns units
// [16w,16w+16) x 3 gates (12 MFMAs/step). Operand-swapped (Whh = A regs,
// h = B frag from LDS). Lane (kg,l15): units 16w+4kg..+4, batch half*16+l15.
// LDS-only barrier per step (global prefetch/stores stay in flight).
// xw loads issued 2 steps ahead directly into the px registers.
// ---------------------------------------------------------------------------
__global__ __launch_bounds__(512, 1) void gru_mfma(
    const float* __restrict__ xwT,  // (2,512,2,6144) gru-native v3
    const float* __restrict__ Whh,  // (2,384,128) f32
    const float* __restrict__ bhh,  // (2,384)
    u16* __restrict__ hout)         // (16384,256) bf16
{
  __shared__ __align__(16) u16 h_lds[2][16][136];
  const int t = threadIdx.x;
  const int lane = t & 63, wv = t >> 6;
  const int l15 = lane & 15, kg = lane >> 4;
  const int dir = blockIdx.x & 1, half = blockIdx.x >> 1;
  // Whh A-fragments: row = g*128 + wv*16 + l15, k = kc*32 + kg*8
  s16x8 wa[3][4];
  {
    const float* Wd = Whh + (size_t)dir*49152;
    #pragma unroll
    for (int g = 0; g < 3; g++)
      #pragma unroll
      for (int kc = 0; kc < 4; kc++)
        wa[g][kc] = packfrag(&Wd[(size_t)(g*128 + wv*16 + l15)*128
                                 + kc*32 + kg*8]);
  }
  const f32x4 bhn = *(const f32x4*)&bhh[dir*384 + 256 + wv*16 + kg*4];
  if (t < 272) ((uint4*)h_lds)[t] = make_uint4(0,0,0,0);
  f32x4 hreg = {0.f,0.f,0.f,0.f};
  const long tstep = dir ? -49152L : 49152L;     // bytes per tt step
  const char* xb = (const char*)xwT
      + (((size_t)dir*512 + (dir ? 511 : 0))*2 + half)*24576
      + (size_t)(((wv*4 + kg)*16 + l15)*12)*4;
  f32x4 pa[3], pb[3];
  pa[0] = *(const f32x4*)(xb); pa[1] = *(const f32x4*)(xb+16); pa[2] = *(const f32x4*)(xb+32);
  xb += tstep;
  pb[0] = *(const f32x4*)(xb); pb[1] = *(const f32x4*)(xb+16); pb[2] = *(const f32x4*)(xb+32);
  xb += tstep;
  const int hstep = dir ? -256 : 256;            // u16 units per tt step
  int hoff = ((half*16 + l15)*512 + (dir ? 511 : 0))*256 + dir*128 + wv*16 + kg*4;
  lds_barrier();
  int cur = 0;

#define GSTEP(PX, DOLOAD)                                                   \
  {                                                                         \
    /* extract current xw (register reads; loads below reuse PX regs) */    \
    const f32x4 cxr = PX[0], cxz = PX[1], cxn = PX[2];                      \
    if (DOLOAD){                                                            \
      PX[0] = *(const f32x4*)(xb);                                          \
      PX[1] = *(const f32x4*)(xb+16);                                       \
      PX[2] = *(const f32x4*)(xb+32);                                       \
      xb += tstep;                                                          \
    }                                                                       \
    f32x4 a0 = {0.f,0.f,0.f,0.f}, a1 = a0, a2 = a0;                         \
    _Pragma("unroll")                                                       \
    for (int kc = 0; kc < 4; kc++){                                         \
      const s16x8 hf = *(const s16x8*)&h_lds[cur][l15][kc*32 + kg*8];       \
      a0 = mfma16(wa[0][kc], hf, a0);                                       \
      a1 = mfma16(wa[1][kc], hf, a1);                                       \
      a2 = mfma16(wa[2][kc], hf, a2);                                       \
    }                                                                       \
    float hn[4];                                                            \
    _Pragma("unroll")                                                       \
    for (int r = 0; r < 4; r++){                                            \
      const float rr = fast_sigmoid(cxr[r] + a0[r]);                        \
      const float zz = fast_sigmoid(cxz[r] + a1[r]);                        \
      const float nn = fast_tanh(cxn[r] + rr*(a2[r] + bhn[r]));             \
      hn[r] = fmaf(zz, hreg[r] - nn, nn);                                   \
      hreg[r] = hn[r];                                                      \
    }                                                                       \
    const uint2 hp = make_uint2(pack2(hn[0],hn[1]), pack2(hn[2],hn[3]));    \
    *(uint2*)&h_lds[cur^1][l15][wv*16 + kg*4] = hp;                         \
    *(uint2*)&hout[hoff] = hp;                                              \
    hoff += hstep;                                                          \
    lds_barrier();                                                          \
    cur ^= 1;                                                               \
  }

  for (int ti = 0; ti < 510; ti += 2){
    GSTEP(pa, 1);
    GSTEP(pb, 1);
  }
  GSTEP(pa, 0);   // step 510
  GSTEP(pb, 0);   // step 511
#undef GSTEP
}

__global__ void prefix_kernel(const int* __restrict__ lengths, int* __restrict__ pre){
  if (threadIdx.x == 0 && blockIdx.x == 0){
    int run = 0;
    for (int b = 0; b < 32; b++){ pre[b] = run; run += lengths[b]; }
  }
}

// ---------------------------------------------------------------------------
// Final FC (61 x 256) + ragged masked scatter into d_out (unchanged).
// ---------------------------------------------------------------------------
__global__ __launch_bounds__(256) void fc_kernel(
    const u16* __restrict__ A,      // (16384,256) bf16
    const float* __restrict__ W,    // (61,256)
    const float* __restrict__ bias, // (61)
    const int* __restrict__ lengths,
    const int* __restrict__ pre,
    float* __restrict__ out)
{
  __shared__ __align__(16) float4 Wl[64][61];
  __shared__ __align__(16) float  Al[64][256];
  const int t = threadIdx.x;
  const int row0 = blockIdx.x * 64;
  for (int idx = t; idx < 61*64; idx += 256){
    int c = idx >> 6, k4 = idx & 63;
    Wl[k4][c] = *(const float4*)&W[(size_t)c*256 + k4*4];
  }
  {
    const u32* A32 = (const u32*)(A + (size_t)row0*256);
    for (int idx = t; idx < 8192; idx += 256){
      u32 v = A32[idx];
      int r = idx >> 7, kp = idx & 127;
      Al[r][2*kp]   = bflo(v);
      Al[r][2*kp+1] = bfhi(v);
    }
  }
  __syncthreads();
  const int c = t & 63;
  const int rbase = t >> 6;
  if (c < 61){
    const float bv = bias[c];
    for (int rr = rbase; rr < 64; rr += 4){
      float s0=0,s1=0,s2=0,s3=0;
      const float4* Ap = (const float4*)&Al[rr][0];
      #pragma unroll
      for (int k4 = 0; k4 < 64; k4++){
        const float4 w = Wl[k4][c];
        const float4 a = Ap[k4];
        s0 = fmaf(w.x, a.x, s0);
        s1 = fmaf(w.y, a.y, s1);
        s2 = fmaf(w.z, a.z, s2);
        s3 = fmaf(w.w, a.w, s3);
      }
      const int n = row0 + rr;
      const int b = n >> 9, tt = n & 511;
      if (tt < lengths[b])
        out[(size_t)(pre[b] + tt)*61 + c] = bv + s0+s1+s2+s3;
    }
  }
}

extern "C" void kernel_launch(void* const* d_in, const int* in_sizes, int n_in,
                              void* d_out, int out_size, void* d_ws, size_t ws_size,
                              hipStream_t stream)
{
  const float* x     = (const float*)d_in[0];
  const int*   lens  = (const int*)d_in[1];
  const float* r0Wih = (const float*)d_in[2];
  const float* r0Whh = (const float*)d_in[3];
  const float* r0bih = (const float*)d_in[4];
  const float* r0bhh = (const float*)d_in[5];
  const float* r1Wih = (const float*)d_in[6];
  const float* r1Whh = (const float*)d_in[7];
  const float* r1bih = (const float*)d_in[8];
  const float* r1bhh = (const float*)d_in[9];
  const float* g0Wih = (const float*)d_in[10];
  const float* g0Whh = (const float*)d_in[11];
  const float* g0bih = (const float*)d_in[12];
  const float* g0bhh = (const float*)d_in[13];
  const float* g1Wih = (const float*)d_in[14];
  const float* g1Whh = (const float*)d_in[15];
  const float* g1bih = (const float*)d_in[16];
  const float* g1bhh = (const float*)d_in[17];
  const float* fcW   = (const float*)d_in[18];
  const float* fcb   = (const float*)d_in[19];
  float* out = (float*)d_out;

  char* ws = (char*)d_ws;
  u16*   l0buf = (u16*)(ws);
  float* xwbuf = (float*)(ws);                      // xwT (2,512,2,6144) f32
  u16*   g0out = (u16*)(ws + 50331648);
  u16*   g0Wb  = (u16*)(ws + 58720256);             // 393216 B
  u16*   g1Wb  = (u16*)(ws + 58720256 + 393216);    // 393216 B
  u16*   r1Wb  = (u16*)(ws + 58720256 + 786432);    // 65536 B
  float* biasb = (float*)(ws + 58720256 + 851968);  // 512 B
  u16*   g1out = (u16*)(ws + 58720256);             // overwrites prep late
  u16*   rnn1  = (u16*)(ws + 67108864);
  int*   pre   = (int*)(ws + 75497472);

  prep_kernel<<<768, 256, 0, stream>>>(g0Wih, g1Wih, r1Wih, r1bih, r1bhh,
                                       g0Wb, g1Wb, r1Wb, biasb);
  for (int c = 0; c < NF_/CH_; c++){
    l0_mfma<<<dim3(CH_/16, 2), 256, 0, stream>>>(
        x + (size_t)c*CH_*2048, r0Wih, r0Whh, r0bih, r0bhh, l0buf);
    l1f_mfma<<<dim3(CH_/16), 256, 0, stream>>>(
        l0buf, r1Wih, r1Whh, r1bih, r1bhh, rnn1 + (size_t)c*CH_*256);
    mfma_gemm<<<dim3(128/32, CH_/64), 256, 0, stream>>>(
        l0buf + 15*256, 4096, r1Wb, 256, biasb,
        (float*)nullptr, rnn1 + (size_t)c*CH_*256 + 128, 256, 1);
  }
  // GRU layer 0
  gemm_xw<<<dim3(768/32, NF_/64), 256, 0, stream>>>(
      rnn1, 256, g0Wb, 256, g0bih, g0bhh, xwbuf);
  gru_mfma<<<4, 512, 0, stream>>>(xwbuf, g0Whh, g0bhh, g0out);
  // GRU layer 1
  gemm_xw<<<dim3(768/32, NF_/64), 256, 0, stream>>>(
      g0out, 256, g1Wb, 256, g1bih, g1bhh, xwbuf);
  gru_mfma<<<4, 512, 0, stream>>>(xwbuf, g1Whh, g1bhh, g1out);
  // FC + ragged scatter
  prefix_kernel<<<1, 64, 0, stream>>>(lens, pre);
  fc_kernel<<<NF_/64, 256, 0, stream>>>(g1out, fcW, fcb, lens, pre, out);
}

// Round 8
// 1002.085 us; speedup vs baseline: 1.1881x; 1.0310x over previous
//
#include <hip/hip_runtime.h>
#include <hip/hip_bf16.h>

#define B_ 32
#define T_ 512
#define L_ 16
#define F_ 128
#define H_ 128
#define C_ 61
#define NF_ (B_*T_)   // 16384 frames
#define CH_ 4096      // frames per rnn1 chunk

typedef unsigned int u32;
typedef unsigned short u16;
typedef __attribute__((ext_vector_type(8))) short s16x8;
typedef __attribute__((ext_vector_type(4))) float f32x4;

__device__ __forceinline__ float bflo(u32 v){ return __uint_as_float(v << 16); }
__device__ __forceinline__ float bfhi(u32 v){ return __uint_as_float(v & 0xffff0000u); }
__device__ __forceinline__ u16 f2bf(float f){
  u32 u = __float_as_uint(f);
  u += 0x7fffu + ((u >> 16) & 1u);
  return (u16)(u >> 16);
}
__device__ __forceinline__ u32 pack2(float a, float b){
  return (u32)f2bf(a) | ((u32)f2bf(b) << 16);
}
__device__ __forceinline__ u32 cvt_pk_bf16(float a, float b){
  u32 d;
  asm("v_cvt_pk_bf16_f32 %0, %1, %2" : "=v"(d) : "v"(a), "v"(b));
  return d;
}
__device__ __forceinline__ float fast_tanh(float x){
  float e = __expf(2.f*x);
  return 1.f - 2.f*__builtin_amdgcn_rcpf(e + 1.f);
}
__device__ __forceinline__ float fast_sigmoid(float x){
  return __builtin_amdgcn_rcpf(1.f + __expf(-x));
}
__device__ __forceinline__ f32x4 mfma16(s16x8 a, s16x8 b, f32x4 c){
  return __builtin_amdgcn_mfma_f32_16x16x32_bf16(a, b, c, 0, 0, 0);
}
// LDS-only barrier: does NOT drain vmcnt (global prefetch loads / stores
// stay in flight), unlike __syncthreads which drains vmcnt(0).
__device__ __forceinline__ void lds_barrier(){
  asm volatile("s_waitcnt lgkmcnt(0)\n\ts_barrier" ::: "memory");
}
// pack 8 consecutive f32 (two float4) into a bf16x8 fragment, k-order
__device__ __forceinline__ s16x8 packfrag(const float* p){
  const float4 a = *(const float4*)p;
  const float4 b = *(const float4*)(p+4);
  union { s16x8 v; u32 w[4]; } f;
  f.w[0]=pack2(a.x,a.y); f.w[1]=pack2(a.z,a.w);
  f.w[2]=pack2(b.x,b.y); f.w[3]=pack2(b.z,b.w);
  return f.v;
}

// ---------------------------------------------------------------------------
// rnn1 layer 0 via MFMA. 16 frames/WG (512 WGs -> 2/CU). Bias folded into
// accumulator init; LDS-only barriers.
// ---------------------------------------------------------------------------
__global__ __launch_bounds__(256) void l0_mfma(
    const float* __restrict__ x,      // (CH,16,128) chunk base
    const float* __restrict__ Wih,    // (2,128,128)
    const float* __restrict__ Whh,    // (2,128,128)
    const float* __restrict__ bih,    // (2,128)
    const float* __restrict__ bhh,    // (2,128)
    u16* __restrict__ out)            // (CH,16,256) bf16
{
  __shared__ __align__(16) u16 Hb[2][16][136];
  __shared__ __align__(16) u16 Xb[2][16][136];
  const int t = threadIdx.x;
  const int lane = t & 63, wv = t >> 6;
  const int l15 = lane & 15, kg = lane >> 4;
  const int dir = blockIdx.y;
  const int f0 = blockIdx.x * 16;
  s16x8 wih[2][4], whh[2][4];
  {
    const float* Wid = Wih + dir*16384;
    const float* Whd = Whh + dir*16384;
    #pragma unroll
    for (int nt = 0; nt < 2; nt++){
      const int u = wv*32 + nt*16 + l15;
      #pragma unroll
      for (int kc = 0; kc < 4; kc++){
        const int k = kc*32 + kg*8;
        wih[nt][kc] = packfrag(&Wid[u*128 + k]);
        whh[nt][kc] = packfrag(&Whd[u*128 + k]);
      }
    }
  }
  const float bv0 = bih[dir*128 + wv*32 + l15]      + bhh[dir*128 + wv*32 + l15];
  const float bv1 = bih[dir*128 + wv*32 + 16 + l15] + bhh[dir*128 + wv*32 + 16 + l15];
  const f32x4 bs0 = {bv0,bv0,bv0,bv0}, bs1 = {bv1,bv1,bv1,bv1};
  const int sr = t >> 4, sc8 = (t & 15) * 8;   // stage: frame row, col (8 f32)
  for (int idx = t; idx < 272; idx += 256)
    ((uint4*)&Hb[0][0][0])[idx] = make_uint4(0,0,0,0);
  {
    const int s0 = dir ? 15 : 0;
    const float4* xp = (const float4*)&x[(size_t)(f0+sr)*2048 + s0*128 + sc8];
    const float4 v0 = xp[0], v1 = xp[1];
    *(uint4*)&Xb[0][sr][sc8] = make_uint4(pack2(v0.x,v0.y),pack2(v0.z,v0.w),
                                          pack2(v1.x,v1.y),pack2(v1.z,v1.w));
  }
  lds_barrier();
  int cur = 0;
  for (int st = 0; st < 16; st++){
    const int s = dir ? (15-st) : st;
    float4 p0,p1;
    if (st < 15){
      const int sn = dir ? (14-st) : (st+1);
      const float4* xp = (const float4*)&x[(size_t)(f0+sr)*2048 + sn*128 + sc8];
      p0 = xp[0]; p1 = xp[1];
    }
    f32x4 acc0 = bs0, acc1 = bs1;
    #pragma unroll
    for (int kc = 0; kc < 4; kc++){
      const int ko = kc*32 + kg*8;
      const s16x8 ax = *(const s16x8*)&Xb[cur][l15][ko];
      const s16x8 ah = *(const s16x8*)&Hb[cur][l15][ko];
      acc0 = mfma16(ax, wih[0][kc], acc0);
      acc1 = mfma16(ax, wih[1][kc], acc1);
      acc0 = mfma16(ah, whh[0][kc], acc0);
      acc1 = mfma16(ah, whh[1][kc], acc1);
    }
    const int u0 = wv*32 + l15, u1 = wv*32 + 16 + l15;
    u16* op = out + (size_t)f0*4096 + s*256 + dir*128;
    #pragma unroll
    for (int r = 0; r < 4; r++){
      const int m = kg*4 + r;
      const u16 h0 = f2bf(fast_tanh(acc0[r]));
      const u16 h1 = f2bf(fast_tanh(acc1[r]));
      Hb[cur^1][m][u0] = h0;
      Hb[cur^1][m][u1] = h1;
      op[(size_t)m*4096 + u0] = h0;
      op[(size_t)m*4096 + u1] = h1;
    }
    if (st < 15){
      *(uint4*)&Xb[cur^1][sr][sc8] = make_uint4(pack2(p0.x,p0.y),pack2(p0.z,p0.w),
                                                pack2(p1.x,p1.y),pack2(p1.z,p1.w));
    }
    lds_barrier();
    cur ^= 1;
  }
}

// ---------------------------------------------------------------------------
// rnn1 layer 1 FORWARD via MFMA, 16 frames/WG (LDS-only barriers).
// ---------------------------------------------------------------------------
__global__ __launch_bounds__(256) void l1f_mfma(
    const u16* __restrict__ U,        // (CH,16,256) bf16
    const float* __restrict__ Wih,    // (2,128,256) dir0
    const float* __restrict__ Whh,    // (2,128,128) dir0
    const float* __restrict__ bih,    // (2,128)
    const float* __restrict__ bhh,
    u16* __restrict__ out)            // rnn1 rows (ld 256), cols 0..127
{
  __shared__ __align__(16) u16 Hb[2][16][136];
  __shared__ __align__(16) u16 Xb[2][16][264];
  const int t = threadIdx.x;
  const int lane = t & 63, wv = t >> 6;
  const int l15 = lane & 15, kg = lane >> 4;
  const int f0 = blockIdx.x * 16;
  s16x8 wih[2][8], whh[2][4];
  {
    #pragma unroll
    for (int nt = 0; nt < 2; nt++){
      const int u = wv*32 + nt*16 + l15;
      #pragma unroll
      for (int kc = 0; kc < 8; kc++)
        wih[nt][kc] = packfrag(&Wih[u*256 + kc*32 + kg*8]);
      #pragma unroll
      for (int kc = 0; kc < 4; kc++)
        whh[nt][kc] = packfrag(&Whh[u*128 + kc*32 + kg*8]);
    }
  }
  const float bv0 = bih[wv*32 + l15]      + bhh[wv*32 + l15];
  const float bv1 = bih[wv*32 + 16 + l15] + bhh[wv*32 + 16 + l15];
  const f32x4 bs0 = {bv0,bv0,bv0,bv0}, bs1 = {bv1,bv1,bv1,bv1};
  const int sr = t >> 4, scu = (t & 15) * 16;
  for (int idx = t; idx < 272; idx += 256)
    ((uint4*)&Hb[0][0][0])[idx] = make_uint4(0,0,0,0);
  {
    const uint4* up = (const uint4*)&U[(size_t)(f0+sr)*4096 + scu];
    uint4 c0 = up[0], c1 = up[1];
    *(uint4*)&Xb[0][sr][scu]   = c0;
    *(uint4*)&Xb[0][sr][scu+8] = c1;
  }
  lds_barrier();
  int cur = 0;
  for (int st = 0; st < 16; st++){
    uint4 c0,c1;
    if (st < 15){
      const uint4* up = (const uint4*)&U[(size_t)(f0+sr)*4096 + (st+1)*256 + scu];
      c0 = up[0]; c1 = up[1];
    }
    f32x4 acc0 = bs0, acc1 = bs1;
    #pragma unroll
    for (int kc = 0; kc < 8; kc++){
      const s16x8 ax = *(const s16x8*)&Xb[cur][l15][kc*32 + kg*8];
      acc0 = mfma16(ax, wih[0][kc], acc0);
      acc1 = mfma16(ax, wih[1][kc], acc1);
    }
    #pragma unroll
    for (int kc = 0; kc < 4; kc++){
      const s16x8 ah = *(const s16x8*)&Hb[cur][l15][kc*32 + kg*8];
      acc0 = mfma16(ah, whh[0][kc], acc0);
      acc1 = mfma16(ah, whh[1][kc], acc1);
    }
    const int u0 = wv*32 + l15, u1 = wv*32 + 16 + l15;
    #pragma unroll
    for (int r = 0; r < 4; r++){
      const int m = kg*4 + r;
      const u16 h0 = f2bf(fast_tanh(acc0[r]));
      const u16 h1 = f2bf(fast_tanh(acc1[r]));
      Hb[cur^1][m][u0] = h0;
      Hb[cur^1][m][u1] = h1;
      if (st == 15){
        out[(size_t)(f0+m)*256 + u0] = h0;
        out[(size_t)(f0+m)*256 + u1] = h1;
      }
    }
    if (st < 15){
      *(uint4*)&Xb[cur^1][sr][scu]   = c0;
      *(uint4*)&Xb[cur^1][sr][scu+8] = c1;
    }
    lds_barrier();
    cur ^= 1;
  }
}

// ---------------------------------------------------------------------------
// Register-only MFMA GEMM: C(M,N) = A @ Wb^T + bias [tanh], bf16/f32 out.
// ---------------------------------------------------------------------------
__global__ __launch_bounds__(256) void mfma_gemm(
    const u16* __restrict__ A, int lda,
    const u16* __restrict__ Wb, int K,
    const float* __restrict__ bias,
    float* __restrict__ Cf, u16* __restrict__ Cb, int ldc, int act)
{
  const int t = threadIdx.x;
  const int lane = t & 63, wv = t >> 6;
  const int l15 = lane & 15, kg = lane >> 4;
  const int n0 = blockIdx.x * 32;
  const int m0 = blockIdx.y * 64 + wv*16;
  const u16* Ap = A + (size_t)(m0 + l15)*lda + kg*8;
  const u16* W0 = Wb + (size_t)(n0 + l15)*K + kg*8;
  const u16* W1 = Wb + (size_t)(n0 + 16 + l15)*K + kg*8;
  f32x4 acc0 = {0.f,0.f,0.f,0.f}, acc1 = acc0;
  #pragma unroll 4
  for (int kc = 0; kc < K/32; kc++){
    const s16x8 a  = *(const s16x8*)(Ap + kc*32);
    const s16x8 b0 = *(const s16x8*)(W0 + kc*32);
    const s16x8 b1 = *(const s16x8*)(W1 + kc*32);
    acc0 = mfma16(a, b0, acc0);
    acc1 = mfma16(a, b1, acc1);
  }
  const int col0 = n0 + l15, col1 = n0 + 16 + l15;
  const float bv0 = bias[col0], bv1 = bias[col1];
  #pragma unroll
  for (int r = 0; r < 4; r++){
    const int row = m0 + kg*4 + r;
    float v0 = acc0[r] + bv0, v1 = acc1[r] + bv1;
    if (act){ v0 = fast_tanh(v0); v1 = fast_tanh(v1); }
    if (Cf){
      Cf[(size_t)row*ldc + col0] = v0;
      Cf[(size_t)row*ldc + col1] = v1;
    } else {
      Cb[(size_t)row*ldc + col0] = f2bf(v0);
      Cb[(size_t)row*ldc + col1] = f2bf(v1);
    }
  }
}

// ---------------------------------------------------------------------------
// xw GEMM -> gru-native v3 layout (unchanged from round 7).
// ---------------------------------------------------------------------------
__global__ __launch_bounds__(256) void gemm_xw(
    const u16* __restrict__ A, int lda,
    const u16* __restrict__ Wb, int K,
    const float* __restrict__ bih, const float* __restrict__ bhhp,
    float* __restrict__ xwT)
{
  const int t = threadIdx.x;
  const int lane = t & 63, wv = t >> 6;
  const int l15 = lane & 15, kg = lane >> 4;
  const int n0 = blockIdx.x * 32;
  const int m0 = blockIdx.y * 64 + wv*16;
  const u16* Ap = A + (size_t)(m0 + l15)*lda + kg*8;
  const u16* W0 = Wb + (size_t)(n0 + l15)*K + kg*8;
  const u16* W1 = Wb + (size_t)(n0 + 16 + l15)*K + kg*8;
  f32x4 acc0 = {0.f,0.f,0.f,0.f}, acc1 = acc0;
  #pragma unroll 4
  for (int kc = 0; kc < K/32; kc++){
    const s16x8 a  = *(const s16x8*)(Ap + kc*32);
    const s16x8 b0 = *(const s16x8*)(W0 + kc*32);
    const s16x8 b1 = *(const s16x8*)(W1 + kc*32);
    acc0 = mfma16(a, b0, acc0);
    acc1 = mfma16(a, b1, acc1);
  }
  const int col0 = n0 + l15, col1 = n0 + 16 + l15;
  const int row0 = m0 + kg*4;
  const int b = row0 >> 9, tt0 = row0 & 511;
  const int half = b >> 4, bl = b & 15;
  float bv0 = bih[col0], bv1 = bih[col1];
  {
    const int c0 = col0 >= 384 ? col0-384 : col0;
    const int c1 = col1 >= 384 ? col1-384 : col1;
    if ((c0 >> 7) < 2) bv0 += bhhp[col0];
    if ((c1 >> 7) < 2) bv1 += bhhp[col1];
  }
  size_t i0, i1;
  {
    const int d0 = col0 >= 384 ? 1 : 0;
    const int c  = col0 - d0*384;
    const int g = c >> 7, cu = c & 127;
    i0 = (((size_t)d0*512 + tt0)*2 + half)*6144
         + (size_t)(((cu>>4)*4 + ((cu>>2)&3))*16 + bl)*12 + g*4 + (cu&3);
  }
  {
    const int d1 = col1 >= 384 ? 1 : 0;
    const int c  = col1 - d1*384;
    const int g = c >> 7, cu = c & 127;
    i1 = (((size_t)d1*512 + tt0)*2 + half)*6144
         + (size_t)(((cu>>4)*4 + ((cu>>2)&3))*16 + bl)*12 + g*4 + (cu&3);
  }
  #pragma unroll
  for (int r = 0; r < 4; r++){
    xwT[i0 + (size_t)r*12288] = acc0[r] + bv0;
    xwT[i1 + (size_t)r*12288] = acc1[r] + bv1;
  }
}

// ---------------------------------------------------------------------------
// Weight prep (unchanged).
// ---------------------------------------------------------------------------
__global__ __launch_bounds__(256) void prep_kernel(
    const float* __restrict__ g0W, const float* __restrict__ g1W,
    const float* __restrict__ r1Wih,
    const float* __restrict__ r1bih, const float* __restrict__ r1bhh,
    u16* __restrict__ g0o, u16* __restrict__ g1o, u16* __restrict__ r1o,
    float* __restrict__ bo)
{
  const int i = blockIdx.x*256 + threadIdx.x;
  if (i < 196608){ g0o[i] = f2bf(g0W[i]); g1o[i] = f2bf(g1W[i]); }
  if (i < 32768)   r1o[i] = f2bf(r1Wih[32768 + i]);
  if (i < 128)     bo[i]  = r1bih[128+i] + r1bhh[128+i];
}

// ---------------------------------------------------------------------------
// GRU scan v4. Same structure as v3 (4 WGs x 8 waves, operand-swapped,
// LDS-only barriers, 2-step xw prefetch) with VALU trimming:
//  - MFMA accumulators init directly from xw (r,z gates) / bhn (n gate)
//  - h packing via v_cvt_pk_bf16_f32
//  - s_setprio(1) around the MFMA cluster
// ---------------------------------------------------------------------------
__global__ __launch_bounds__(512, 1) void gru_mfma(
    const float* __restrict__ xwT,  // (2,512,2,6144) gru-native v3
    const float* __restrict__ Whh,  // (2,384,128) f32
    const float* __restrict__ bhh,  // (2,384)
    u16* __restrict__ hout)         // (16384,256) bf16
{
  __shared__ __align__(16) u16 h_lds[2][16][136];
  const int t = threadIdx.x;
  const int lane = t & 63, wv = t >> 6;
  const int l15 = lane & 15, kg = lane >> 4;
  const int dir = blockIdx.x & 1, half = blockIdx.x >> 1;
  // Whh A-fragments: row = g*128 + wv*16 + l15, k = kc*32 + kg*8
  s16x8 wa[3][4];
  {
    const float* Wd = Whh + (size_t)dir*49152;
    #pragma unroll
    for (int g = 0; g < 3; g++)
      #pragma unroll
      for (int kc = 0; kc < 4; kc++)
        wa[g][kc] = packfrag(&Wd[(size_t)(g*128 + wv*16 + l15)*128
                                 + kc*32 + kg*8]);
  }
  const f32x4 bhn = *(const f32x4*)&bhh[dir*384 + 256 + wv*16 + kg*4];
  if (t < 272) ((uint4*)h_lds)[t] = make_uint4(0,0,0,0);
  f32x4 hreg = {0.f,0.f,0.f,0.f};
  const long tstep = dir ? -49152L : 49152L;     // bytes per tt step
  const char* xb = (const char*)xwT
      + (((size_t)dir*512 + (dir ? 511 : 0))*2 + half)*24576
      + (size_t)(((wv*4 + kg)*16 + l15)*12)*4;
  f32x4 pa[3], pb[3];
  pa[0] = *(const f32x4*)(xb); pa[1] = *(const f32x4*)(xb+16); pa[2] = *(const f32x4*)(xb+32);
  xb += tstep;
  pb[0] = *(const f32x4*)(xb); pb[1] = *(const f32x4*)(xb+16); pb[2] = *(const f32x4*)(xb+32);
  xb += tstep;
  const int hstep = dir ? -256 : 256;            // u16 units per tt step
  int hoff = ((half*16 + l15)*512 + (dir ? 511 : 0))*256 + dir*128 + wv*16 + kg*4;
  lds_barrier();
  int cur = 0;

#define GSTEP(PX, DOLOAD)                                                   \
  {                                                                         \
    /* current xw into accumulators; n-gate xw kept separate */             \
    f32x4 a0 = PX[0], a1 = PX[1], a2 = bhn;                                 \
    const f32x4 cxn = PX[2];                                                \
    if (DOLOAD){                                                            \
      PX[0] = *(const f32x4*)(xb);                                          \
      PX[1] = *(const f32x4*)(xb+16);                                       \
      PX[2] = *(const f32x4*)(xb+32);                                       \
      xb += tstep;                                                          \
    }                                                                       \
    __builtin_amdgcn_s_setprio(1);                                          \
    _Pragma("unroll")                                                       \
    for (int kc = 0; kc < 4; kc++){                                         \
      const s16x8 hf = *(const s16x8*)&h_lds[cur][l15][kc*32 + kg*8];       \
      a0 = mfma16(wa[0][kc], hf, a0);                                       \
      a1 = mfma16(wa[1][kc], hf, a1);                                       \
      a2 = mfma16(wa[2][kc], hf, a2);                                       \
    }                                                                       \
    __builtin_amdgcn_s_setprio(0);                                          \
    float hn[4];                                                            \
    _Pragma("unroll")                                                       \
    for (int r = 0; r < 4; r++){                                            \
      const float rr = fast_sigmoid(a0[r]);                                 \
      const float zz = fast_sigmoid(a1[r]);                                 \
      const float nn = fast_tanh(fmaf(rr, a2[r], cxn[r]));                  \
      hn[r] = fmaf(zz, hreg[r] - nn, nn);                                   \
      hreg[r] = hn[r];                                                      \
    }                                                                       \
    const uint2 hp = make_uint2(cvt_pk_bf16(hn[0],hn[1]),                   \
                                cvt_pk_bf16(hn[2],hn[3]));                  \
    *(uint2*)&h_lds[cur^1][l15][wv*16 + kg*4] = hp;                         \
    *(uint2*)&hout[hoff] = hp;                                              \
    hoff += hstep;                                                          \
    lds_barrier();                                                          \
    cur ^= 1;                                                               \
  }

  for (int ti = 0; ti < 510; ti += 2){
    GSTEP(pa, 1);
    GSTEP(pb, 1);
  }
  GSTEP(pa, 0);   // step 510
  GSTEP(pb, 0);   // step 511
#undef GSTEP
}

__global__ void prefix_kernel(const int* __restrict__ lengths, int* __restrict__ pre){
  if (threadIdx.x == 0 && blockIdx.x == 0){
    int run = 0;
    for (int b = 0; b < 32; b++){ pre[b] = run; run += lengths[b]; }
  }
}

// ---------------------------------------------------------------------------
// Final FC (61 x 256) + ragged masked scatter into d_out (unchanged).
// ---------------------------------------------------------------------------
__global__ __launch_bounds__(256) void fc_kernel(
    const u16* __restrict__ A,      // (16384,256) bf16
    const float* __restrict__ W,    // (61,256)
    const float* __restrict__ bias, // (61)
    const int* __restrict__ lengths,
    const int* __restrict__ pre,
    float* __restrict__ out)
{
  __shared__ __align__(16) float4 Wl[64][61];
  __shared__ __align__(16) float  Al[64][256];
  const int t = threadIdx.x;
  const int row0 = blockIdx.x * 64;
  for (int idx = t; idx < 61*64; idx += 256){
    int c = idx >> 6, k4 = idx & 63;
    Wl[k4][c] = *(const float4*)&W[(size_t)c*256 + k4*4];
  }
  {
    const u32* A32 = (const u32*)(A + (size_t)row0*256);
    for (int idx = t; idx < 8192; idx += 256){
      u32 v = A32[idx];
      int r = idx >> 7, kp = idx & 127;
      Al[r][2*kp]   = bflo(v);
      Al[r][2*kp+1] = bfhi(v);
    }
  }
  __syncthreads();
  const int c = t & 63;
  const int rbase = t >> 6;
  if (c < 61){
    const float bv = bias[c];
    for (int rr = rbase; rr < 64; rr += 4){
      float s0=0,s1=0,s2=0,s3=0;
      const float4* Ap = (const float4*)&Al[rr][0];
      #pragma unroll
      for (int k4 = 0; k4 < 64; k4++){
        const float4 w = Wl[k4][c];
        const float4 a = Ap[k4];
        s0 = fmaf(w.x, a.x, s0);
        s1 = fmaf(w.y, a.y, s1);
        s2 = fmaf(w.z, a.z, s2);
        s3 = fmaf(w.w, a.w, s3);
      }
      const int n = row0 + rr;
      const int b = n >> 9, tt = n & 511;
      if (tt < lengths[b])
        out[(size_t)(pre[b] + tt)*61 + c] = bv + s0+s1+s2+s3;
    }
  }
}

extern "C" void kernel_launch(void* const* d_in, const int* in_sizes, int n_in,
                              void* d_out, int out_size, void* d_ws, size_t ws_size,
                              hipStream_t stream)
{
  const float* x     = (const float*)d_in[0];
  const int*   lens  = (const int*)d_in[1];
  const float* r0Wih = (const float*)d_in[2];
  const float* r0Whh = (const float*)d_in[3];
  const float* r0bih = (const float*)d_in[4];
  const float* r0bhh = (const float*)d_in[5];
  const float* r1Wih = (const float*)d_in[6];
  const float* r1Whh = (const float*)d_in[7];
  const float* r1bih = (const float*)d_in[8];
  const float* r1bhh = (const float*)d_in[9];
  const float* g0Wih = (const float*)d_in[10];
  const float* g0Whh = (const float*)d_in[11];
  const float* g0bih = (const float*)d_in[12];
  const float* g0bhh = (const float*)d_in[13];
  const float* g1Wih = (const float*)d_in[14];
  const float* g1Whh = (const float*)d_in[15];
  const float* g1bih = (const float*)d_in[16];
  const float* g1bhh = (const float*)d_in[17];
  const float* fcW   = (const float*)d_in[18];
  const float* fcb   = (const float*)d_in[19];
  float* out = (float*)d_out;

  char* ws = (char*)d_ws;
  u16*   l0buf = (u16*)(ws);
  float* xwbuf = (float*)(ws);                      // xwT (2,512,2,6144) f32
  u16*   g0out = (u16*)(ws + 50331648);
  u16*   g0Wb  = (u16*)(ws + 58720256);             // 393216 B
  u16*   g1Wb  = (u16*)(ws + 58720256 + 393216);    // 393216 B
  u16*   r1Wb  = (u16*)(ws + 58720256 + 786432);    // 65536 B
  float* biasb = (float*)(ws + 58720256 + 851968);  // 512 B
  u16*   g1out = (u16*)(ws + 58720256);             // overwrites prep late
  u16*   rnn1  = (u16*)(ws + 67108864);
  int*   pre   = (int*)(ws + 75497472);

  prep_kernel<<<768, 256, 0, stream>>>(g0Wih, g1Wih, r1Wih, r1bih, r1bhh,
                                       g0Wb, g1Wb, r1Wb, biasb);
  for (int c = 0; c < NF_/CH_; c++){
    l0_mfma<<<dim3(CH_/16, 2), 256, 0, stream>>>(
        x + (size_t)c*CH_*2048, r0Wih, r0Whh, r0bih, r0bhh, l0buf);
    l1f_mfma<<<dim3(CH_/16), 256, 0, stream>>>(
        l0buf, r1Wih, r1Whh, r1bih, r1bhh, rnn1 + (size_t)c*CH_*256);
    mfma_gemm<<<dim3(128/32, CH_/64), 256, 0, stream>>>(
        l0buf + 15*256, 4096, r1Wb, 256, biasb,
        (float*)nullptr, rnn1 + (size_t)c*CH_*256 + 128, 256, 1);
  }
  // GRU layer 0
  gemm_xw<<<dim3(768/32, NF_/64), 256, 0, stream>>>(
      rnn1, 256, g0Wb, 256, g0bih, g0bhh, xwbuf);
  gru_mfma<<<4, 512, 0, stream>>>(xwbuf, g0Whh, g0bhh, g0out);
  // GRU layer 1
  gemm_xw<<<dim3(768/32, NF_/64), 256, 0, stream>>>(
      g0out, 256, g1Wb, 256, g1bih, g1bhh, xwbuf);
  gru_mfma<<<4, 512, 0, stream>>>(xwbuf, g1Whh, g1bhh, g1out);
  // FC + ragged scatter
  prefix_kernel<<<1, 64, 0, stream>>>(lens, pre);
  fc_kernel<<<NF_/64, 256, 0, stream>>>(g1out, fcW, fcb, lens, pre, out);
}